// Round 4
// baseline (311.054 us; speedup 1.0000x reference)
//
#include <hip/hip_runtime.h>
#include <hip/hip_bf16.h>

#define NB 8
#define CH 256
#define NN 4096
#define CQK 32
#define LOG2E 1.4426950408889634f

typedef __attribute__((ext_vector_type(4))) float f32x4;
typedef __attribute__((ext_vector_type(8))) short bf16x8;
typedef unsigned short u16;

// f32 -> bf16 round-to-nearest-even (no NaN inputs here)
static __device__ __forceinline__ u16 f2bf(float f) {
  unsigned int u = __float_as_uint(f);
  unsigned int r = (u + 0x7fffu + ((u >> 16) & 1u)) >> 16;
  return (u16)r;
}

// Raw barrier: only drain LDS ops (write visibility); global loads stay in
// flight across it (counted vmcnt waits appear at the consumption sites).
#define PBARRIER() do {                                   \
  asm volatile("s_waitcnt lgkmcnt(0)" ::: "memory");      \
  __builtin_amdgcn_s_barrier();                           \
  __builtin_amdgcn_sched_barrier(0);                      \
  asm volatile("" ::: "memory");                          \
} while (0)

// ---------------------------------------------------------------------------
// Kernel 1: weights -> bf16. Wqk = [Wq*log2e ; Wk] (64 x 256); bqk likewise.
// ---------------------------------------------------------------------------
__global__ void prep_weights(const float* __restrict__ Wq, const float* __restrict__ bq,
                             const float* __restrict__ Wk, const float* __restrict__ bk,
                             const float* __restrict__ Wv,
                             u16* __restrict__ Wqk, u16* __restrict__ Wvb,
                             float* __restrict__ bqk) {
  int i = blockIdx.x * 256 + threadIdx.x;
  if (i < 64 * 256) {
    int o = i >> 8, c = i & 255;
    float w = (o < 32) ? Wq[o * 256 + c] * LOG2E : Wk[(o - 32) * 256 + c];
    Wqk[i] = f2bf(w);
  }
  if (i < 256 * 256) {
    Wvb[i] = f2bf(Wv[i]);
  }
  if (i < 64) bqk[i] = (i < 32) ? bq[i] * LOG2E : bk[i - 32];
}

// ---------------------------------------------------------------------------
// Kernel 2: x [B,C,N] f32 -> xT [B,N,C] bf16  (LDS tile transpose)
// ---------------------------------------------------------------------------
__global__ __launch_bounds__(256) void transpose_x(const float* __restrict__ x,
                                                   u16* __restrict__ xT) {
  __shared__ u16 t[64][66];
  const int n0 = blockIdx.x * 64, c0 = blockIdx.y * 64, b = blockIdx.z;
  const int tid = threadIdx.x;
  const int nl = tid & 63, cl = tid >> 6;
  const float* xp = x + ((size_t)b * CH + c0) * NN + n0;
#pragma unroll
  for (int p = 0; p < 16; ++p) {
    int c = p * 4 + cl;
    t[c][nl] = f2bf(xp[(size_t)c * NN + nl]);
  }
  __syncthreads();
  u16* op = xT + ((size_t)b * NN + n0) * CH + c0;
#pragma unroll
  for (int p = 0; p < 16; ++p) {
    int n = p * 4 + cl;
    op[(size_t)n * CH + nl] = t[nl][n];
  }
}

// ---------------------------------------------------------------------------
// Kernel 3: projection GEMM (bf16 MFMA, K=256, fragments direct from global).
// out[row, col] = sum_k A[row,k]*B[col,k] + bias.
// ---------------------------------------------------------------------------
__global__ __launch_bounds__(256) void gemm_proj(
    const u16* __restrict__ A, long long a_bs,
    const u16* __restrict__ Bm, long long b_bs,
    const float* __restrict__ bias_r, const float* __restrict__ bias_c,
    int has_br, int has_bc,
    u16* __restrict__ out, long long out_bs, int out_stride) {
  const int m0 = blockIdx.x * 64, c0 = blockIdx.y * 64, b = blockIdx.z;
  const int tid = threadIdx.x, w = tid >> 6, l = tid & 63, g = l >> 4, lr = l & 15;
  const f32x4 fzero = {0.f, 0.f, 0.f, 0.f};

  const u16* Ap = A + (size_t)b * a_bs + (size_t)(m0 + w * 16 + lr) * 256 + g * 8;
  const u16* Bp = Bm + (size_t)b * b_bs + (size_t)(c0 + lr) * 256 + g * 8;

  f32x4 acc[4];
#pragma unroll
  for (int ct = 0; ct < 4; ++ct) acc[ct] = fzero;

#pragma unroll
  for (int kk = 0; kk < 8; ++kk) {
    bf16x8 af = *(const bf16x8*)(Ap + kk * 32);
#pragma unroll
    for (int ct = 0; ct < 4; ++ct) {
      bf16x8 bf = *(const bf16x8*)(Bp + (size_t)ct * 16 * 256 + kk * 32);
      acc[ct] = __builtin_amdgcn_mfma_f32_16x16x32_bf16(af, bf, acc[ct], 0, 0, 0);
    }
  }

#pragma unroll
  for (int ct = 0; ct < 4; ++ct) {
    int col = c0 + ct * 16 + lr;
    float bc = has_bc ? bias_c[col] : 0.f;
#pragma unroll
    for (int r = 0; r < 4; ++r) {
      int row = m0 + w * 16 + g * 4 + r;
      float val = acc[ct][r] + bc + (has_br ? bias_r[row] : 0.f);
      out[(size_t)b * out_bs + (size_t)row * out_stride + col] = f2bf(val);
    }
  }
}

// ---------------------------------------------------------------------------
// Kernel 4 helpers
// ---------------------------------------------------------------------------
static __device__ __forceinline__ void softmax_store(const f32x4& s0, const f32x4& s1,
                                                     char* pbase, int wm, int g, int wswz,
                                                     float& lsum) {
#pragma unroll
  for (int h = 0; h < 2; ++h) {
    const f32x4& s = h ? s1 : s0;
    float p0 = __builtin_amdgcn_exp2f(s[0]);
    float p1 = __builtin_amdgcn_exp2f(s[1]);
    float p2 = __builtin_amdgcn_exp2f(s[2]);
    float p3 = __builtin_amdgcn_exp2f(s[3]);
    lsum += (p0 + p1) + (p2 + p3);
    uint2 pw;  // round-half-up bf16, packed via v_perm
    pw.x = __builtin_amdgcn_perm(__float_as_uint(p1) + 0x8000u,
                                 __float_as_uint(p0) + 0x8000u, 0x07060302u);
    pw.y = __builtin_amdgcn_perm(__float_as_uint(p3) + 0x8000u,
                                 __float_as_uint(p2) + 0x8000u, 0x07060302u);
    *(uint2*)(pbase + (((wm + h) * 32 + g * 8) ^ wswz)) = pw;
  }
}

static __device__ __forceinline__ void pv_accum(const char* prb, int lr, int g,
                                                const bf16x8* vf, f32x4 (*oacc)[2]) {
#pragma unroll
  for (int nt = 0; nt < 4; ++nt) {
    const int row = nt * 16 + lr;
    const int rswz = (row & 7) << 4;
    bf16x8 a0 = *(const bf16x8*)(prb + row * 128 + ((g * 16) ^ rswz));
    bf16x8 a1 = *(const bf16x8*)(prb + row * 128 + ((64 + g * 16) ^ rswz));
#pragma unroll
    for (int ct = 0; ct < 2; ++ct) {
      oacc[nt][ct] = __builtin_amdgcn_mfma_f32_16x16x32_bf16(vf[ct], a0, oacc[nt][ct], 0, 0, 0);
      oacc[nt][ct] = __builtin_amdgcn_mfma_f32_16x16x32_bf16(vf[ct + 2], a1, oacc[nt][ct], 0, 0, 0);
    }
  }
}

// ---------------------------------------------------------------------------
// Kernel 4: fused attention, 8 waves / 512 threads, raw barrier (lgkm-only
// drain) + full-iteration ping-pong prefetch of K and V fragments.
// qk: [B,N,64] bf16 (cols 0-31 = q pre-scaled by log2e, 32-63 = k), v: [B,C,N].
//   QK^T: wave pair (w, w+4) shares n-tile (w&3); wave handles m-half (w>>2)*2.
//   PV:   wave w owns channels w*32..w*32+31; O^T = V * P.
// P double-buffered in LDS, XOR swizzle (byte ^= (row&7)<<4); 1 barrier/iter.
// ---------------------------------------------------------------------------
__global__ __launch_bounds__(512, 4) void attn_fused(
    const u16* __restrict__ qk, const u16* __restrict__ v,
    const float* __restrict__ x, const float* __restrict__ gamma_p,
    float* __restrict__ out) {
  __shared__ __align__(128) char Pb[2][64 * 128];
  __shared__ float lpart[8][16];

  const int b = blockIdx.y;
  const int n0 = blockIdx.x * 64;
  const int tid = threadIdx.x, w = tid >> 6, l = tid & 63, g = l >> 4, lr = l & 15;
  const int wn = w & 3;          // n-tile owned for QK/softmax
  const int wm = (w >> 2) * 2;   // first 16-m subtile owned for QK/softmax
  const float gamma0 = gamma_p[0];
  const f32x4 fzero = {0.f, 0.f, 0.f, 0.f};

  // Q fragment (B-operand): col n = n0 + wn*16 + lr, k = g*8..g*8+7
  bf16x8 qf = *(const bf16x8*)(qk + ((size_t)b * NN + n0 + wn * 16 + lr) * 64 + g * 8);

  const u16* kb = qk + (size_t)b * NN * 64 + (size_t)lr * 64 + 32 + g * 8;  // + m*64
  const u16* vb = v + ((size_t)b * CH + w * 32 + lr) * (size_t)NN + g * 8;  // + ct*16*NN + m

  f32x4 oacc[4][2];
#pragma unroll
  for (int nt = 0; nt < 4; ++nt)
#pragma unroll
    for (int ct = 0; ct < 2; ++ct) oacc[nt][ct] = fzero;
  float lsum = 0.f;

  const int prow = wn * 16 + lr;
  const int wswz = (prow & 7) << 4;

  // prologue: K,V fragments for m-tile 0 (ping set A)
  bf16x8 kfA0, kfA1, kfB0, kfB1, vfA[4], vfB[4];
  kfA0 = *(const bf16x8*)(kb + (size_t)((wm + 0) * 16) * 64);
  kfA1 = *(const bf16x8*)(kb + (size_t)((wm + 1) * 16) * 64);
#pragma unroll
  for (int ct = 0; ct < 2; ++ct) {
    vfA[ct]     = *(const bf16x8*)(vb + (size_t)ct * 16 * NN + 0);
    vfA[ct + 2] = *(const bf16x8*)(vb + (size_t)ct * 16 * NN + 32);
  }

  for (int it2 = 0; it2 < 32; ++it2) {
    const int mB = it2 * 128 + 64;
    const int mN = (it2 * 128 + 128) & (NN - 1);

    // ================= iter A (P -> Pb[0], consumes set A) =================
    f32x4 s0 = __builtin_amdgcn_mfma_f32_16x16x32_bf16(kfA0, qf, fzero, 0, 0, 0);
    f32x4 s1 = __builtin_amdgcn_mfma_f32_16x16x32_bf16(kfA1, qf, fzero, 0, 0, 0);
    // prefetch set B (m-tile mB) — a full iteration of slack
    kfB0 = *(const bf16x8*)(kb + (size_t)(mB + wm * 16) * 64);
    kfB1 = *(const bf16x8*)(kb + (size_t)(mB + wm * 16 + 16) * 64);
#pragma unroll
    for (int ct = 0; ct < 2; ++ct) {
      vfB[ct]     = *(const bf16x8*)(vb + (size_t)ct * 16 * NN + mB);
      vfB[ct + 2] = *(const bf16x8*)(vb + (size_t)ct * 16 * NN + mB + 32);
    }
    softmax_store(s0, s1, Pb[0] + prow * 128, wm, g, wswz, lsum);
    PBARRIER();
    pv_accum(Pb[0], lr, g, vfA, oacc);

    // ================= iter B (P -> Pb[1], consumes set B) =================
    s0 = __builtin_amdgcn_mfma_f32_16x16x32_bf16(kfB0, qf, fzero, 0, 0, 0);
    s1 = __builtin_amdgcn_mfma_f32_16x16x32_bf16(kfB1, qf, fzero, 0, 0, 0);
    // prefetch set A (m-tile mN, wraps to 0 on last iter — harmless)
    kfA0 = *(const bf16x8*)(kb + (size_t)(mN + wm * 16) * 64);
    kfA1 = *(const bf16x8*)(kb + (size_t)(mN + wm * 16 + 16) * 64);
#pragma unroll
    for (int ct = 0; ct < 2; ++ct) {
      vfA[ct]     = *(const bf16x8*)(vb + (size_t)ct * 16 * NN + mN);
      vfA[ct + 2] = *(const bf16x8*)(vb + (size_t)ct * 16 * NN + mN + 32);
    }
    softmax_store(s0, s1, Pb[1] + prow * 128, wm, g, wswz, lsum);
    PBARRIER();
    pv_accum(Pb[1], lr, g, vfB, oacc);
  }

  // ---- epilogue: combine row sums across wave pairs, normalize, write ----
  lsum += __shfl_xor(lsum, 16);
  lsum += __shfl_xor(lsum, 32);
  if (l < 16) lpart[w][lr] = lsum;
  __syncthreads();

  const size_t bbase = (size_t)b * CH * NN;
#pragma unroll
  for (int nt = 0; nt < 4; ++nt) {
    const float linv = 1.f / (lpart[nt][lr] + lpart[nt + 4][lr]);
    const int ncol = n0 + nt * 16 + lr;
#pragma unroll
    for (int ct = 0; ct < 2; ++ct) {
      const int cbase = w * 32 + ct * 16 + g * 4;
#pragma unroll
      for (int r = 0; r < 4; ++r) {
        const size_t off = bbase + (size_t)(cbase + r) * NN + ncol;
        out[off] = gamma0 * (oacc[nt][ct][r] * linv) + x[off];
      }
    }
  }
}

// ---------------------------------------------------------------------------
extern "C" void kernel_launch(void* const* d_in, const int* in_sizes, int n_in,
                              void* d_out, int out_size, void* d_ws, size_t ws_size,
                              hipStream_t stream) {
  const float* x     = (const float*)d_in[0];
  const float* Wq    = (const float*)d_in[1];
  const float* bq    = (const float*)d_in[2];
  const float* Wk    = (const float*)d_in[3];
  const float* bk    = (const float*)d_in[4];
  const float* Wv    = (const float*)d_in[5];
  const float* bv    = (const float*)d_in[6];
  const float* gamma = (const float*)d_in[7];
  float* out = (float*)d_out;

  char* ws = (char*)d_ws;
  u16*   xT  = (u16*)(ws);                 // [B,N,C] bf16   16,777,216 B
  u16*   qkb = (u16*)(ws + 16777216);      // [B,N,64] bf16   4,194,304 B
  u16*   vb  = (u16*)(ws + 20971520);      // [B,C,N] bf16   16,777,216 B
  u16*   Wqk = (u16*)(ws + 37748736);      // [64,256] bf16      32,768 B
  u16*   Wvb = (u16*)(ws + 37781504);      // [256,256] bf16    131,072 B
  float* bqk = (float*)(ws + 37912576);    // [64] f32              256 B

  prep_weights<<<256, 256, 0, stream>>>(Wq, bq, Wk, bk, Wv, Wqk, Wvb, bqk);
  transpose_x<<<dim3(64, 4, 8), 256, 0, stream>>>(x, xT);
  gemm_proj<<<dim3(64, 1, 8), 256, 0, stream>>>(
      xT, (long long)NN * CH, Wqk, 0,
      nullptr, bqk, 0, 1,
      qkb, (long long)NN * 64, 64);
  gemm_proj<<<dim3(4, 64, 8), 256, 0, stream>>>(
      Wvb, 0, xT, (long long)NN * CH,
      bv, nullptr, 1, 0,
      vb, (long long)CH * NN, NN);
  attn_fused<<<dim3(64, 8), 512, 0, stream>>>(qkb, vb, x, gamma, out);
}

// Round 5
// 249.445 us; speedup vs baseline: 1.2470x; 1.2470x over previous
//
#include <hip/hip_runtime.h>
#include <hip/hip_bf16.h>

#define NB 8
#define CH 256
#define NN 4096
#define CQK 32
#define LOG2E 1.4426950408889634f

typedef __attribute__((ext_vector_type(4))) float f32x4;
typedef __attribute__((ext_vector_type(8))) short bf16x8;
typedef unsigned short u16;

// f32 -> bf16 round-to-nearest-even (no NaN inputs here)
static __device__ __forceinline__ u16 f2bf(float f) {
  unsigned int u = __float_as_uint(f);
  unsigned int r = (u + 0x7fffu + ((u >> 16) & 1u)) >> 16;
  return (u16)r;
}

// ---------------------------------------------------------------------------
// Kernel 1: weights -> bf16. Wqk = [Wq*log2e ; Wk] (64 x 256); bqk likewise.
// ---------------------------------------------------------------------------
__global__ void prep_weights(const float* __restrict__ Wq, const float* __restrict__ bq,
                             const float* __restrict__ Wk, const float* __restrict__ bk,
                             const float* __restrict__ Wv,
                             u16* __restrict__ Wqk, u16* __restrict__ Wvb,
                             float* __restrict__ bqk) {
  int i = blockIdx.x * 256 + threadIdx.x;
  if (i < 64 * 256) {
    int o = i >> 8, c = i & 255;
    float w = (o < 32) ? Wq[o * 256 + c] * LOG2E : Wk[(o - 32) * 256 + c];
    Wqk[i] = f2bf(w);
  }
  if (i < 256 * 256) {
    Wvb[i] = f2bf(Wv[i]);
  }
  if (i < 64) bqk[i] = (i < 32) ? bq[i] * LOG2E : bk[i - 32];
}

// ---------------------------------------------------------------------------
// Kernel 2: x [B,C,N] f32 -> xT [B,N,C] bf16  (LDS tile transpose)
// ---------------------------------------------------------------------------
__global__ __launch_bounds__(256) void transpose_x(const float* __restrict__ x,
                                                   u16* __restrict__ xT) {
  __shared__ u16 t[64][66];
  const int n0 = blockIdx.x * 64, c0 = blockIdx.y * 64, b = blockIdx.z;
  const int tid = threadIdx.x;
  const int nl = tid & 63, cl = tid >> 6;
  const float* xp = x + ((size_t)b * CH + c0) * NN + n0;
#pragma unroll
  for (int p = 0; p < 16; ++p) {
    int c = p * 4 + cl;
    t[c][nl] = f2bf(xp[(size_t)c * NN + nl]);
  }
  __syncthreads();
  u16* op = xT + ((size_t)b * NN + n0) * CH + c0;
#pragma unroll
  for (int p = 0; p < 16; ++p) {
    int n = p * 4 + cl;
    op[(size_t)n * CH + nl] = t[nl][n];
  }
}

// ---------------------------------------------------------------------------
// Kernel 3: projection GEMM (bf16 MFMA, K=256, fragments direct from global).
// out[row, col] = sum_k A[row,k]*B[col,k] + bias.
// ---------------------------------------------------------------------------
__global__ __launch_bounds__(256) void gemm_proj(
    const u16* __restrict__ A, long long a_bs,
    const u16* __restrict__ Bm, long long b_bs,
    const float* __restrict__ bias_r, const float* __restrict__ bias_c,
    int has_br, int has_bc,
    u16* __restrict__ out, long long out_bs, int out_stride) {
  const int m0 = blockIdx.x * 64, c0 = blockIdx.y * 64, b = blockIdx.z;
  const int tid = threadIdx.x, w = tid >> 6, l = tid & 63, g = l >> 4, lr = l & 15;
  const f32x4 fzero = {0.f, 0.f, 0.f, 0.f};

  const u16* Ap = A + (size_t)b * a_bs + (size_t)(m0 + w * 16 + lr) * 256 + g * 8;
  const u16* Bp = Bm + (size_t)b * b_bs + (size_t)(c0 + lr) * 256 + g * 8;

  f32x4 acc[4];
#pragma unroll
  for (int ct = 0; ct < 4; ++ct) acc[ct] = fzero;

#pragma unroll
  for (int kk = 0; kk < 8; ++kk) {
    bf16x8 af = *(const bf16x8*)(Ap + kk * 32);
#pragma unroll
    for (int ct = 0; ct < 4; ++ct) {
      bf16x8 bf = *(const bf16x8*)(Bp + (size_t)ct * 16 * 256 + kk * 32);
      acc[ct] = __builtin_amdgcn_mfma_f32_16x16x32_bf16(af, bf, acc[ct], 0, 0, 0);
    }
  }

#pragma unroll
  for (int ct = 0; ct < 4; ++ct) {
    int col = c0 + ct * 16 + lr;
    float bc = has_bc ? bias_c[col] : 0.f;
#pragma unroll
    for (int r = 0; r < 4; ++r) {
      int row = m0 + w * 16 + g * 4 + r;
      float val = acc[ct][r] + bc + (has_br ? bias_r[row] : 0.f);
      out[(size_t)b * out_bs + (size_t)row * out_stride + col] = f2bf(val);
    }
  }
}

// ---------------------------------------------------------------------------
// Kernel 4: fused attention, 8 waves / 512 threads; DS-only barrier drain
// (global K/V prefetch loads stay in flight across the barrier; compiler's
// counted vmcnt waits land at the MFMA consumption sites one iter later).
// Fully inline — no helper calls, no address-escape, no "memory" clobbers
// (round-4 lesson: those forced scratch spills, +105MB WRITE_SIZE).
// qk: [B,N,64] bf16 (cols 0-31 = q pre-scaled by log2e, 32-63 = k), v: [B,C,N].
//   QK^T: wave pair (w, w+4) shares n-tile (w&3); wave handles m-half (w>>2)*2.
//   PV:   wave w owns channels w*32..w*32+31; O^T = V * P.
// P double-buffered in LDS, XOR swizzle (byte ^= (row&7)<<4); 1 barrier/iter.
// ---------------------------------------------------------------------------
__global__ __launch_bounds__(512, 4) void attn_fused(
    const u16* __restrict__ qk, const u16* __restrict__ v,
    const float* __restrict__ x, const float* __restrict__ gamma_p,
    float* __restrict__ out) {
  __shared__ __align__(128) char Pb[2][64 * 128];
  __shared__ float lpart[8][16];

  const int b = blockIdx.y;
  const int n0 = blockIdx.x * 64;
  const int tid = threadIdx.x, w = tid >> 6, l = tid & 63, g = l >> 4, lr = l & 15;
  const int wn = w & 3;          // n-tile owned for QK/softmax
  const int wm = (w >> 2) * 2;   // first 16-m subtile owned for QK/softmax
  const float gamma0 = gamma_p[0];
  const f32x4 fzero = {0.f, 0.f, 0.f, 0.f};

  // Q fragment (B-operand): col n = n0 + wn*16 + lr, k = g*8..g*8+7
  bf16x8 qf = *(const bf16x8*)(qk + ((size_t)b * NN + n0 + wn * 16 + lr) * 64 + g * 8);

  const u16* kb = qk + (size_t)b * NN * 64 + (size_t)lr * 64 + 32 + g * 8;  // + m*64
  const u16* vb = v + ((size_t)b * CH + w * 32 + lr) * (size_t)NN + g * 8;  // + ct*16*NN + m

  f32x4 oacc[4][2];
#pragma unroll
  for (int nt = 0; nt < 4; ++nt)
#pragma unroll
    for (int ct = 0; ct < 2; ++ct) oacc[nt][ct] = fzero;
  float lsum = 0.f;

  const int prow = wn * 16 + lr;
  const int wswz = (prow & 7) << 4;

  // ping-pong register sets; indexed ONLY by compile-time constants
  bf16x8 kf[2][2], vf[2][4];
  kf[0][0] = *(const bf16x8*)(kb + (size_t)((wm + 0) * 16) * 64);
  kf[0][1] = *(const bf16x8*)(kb + (size_t)((wm + 1) * 16) * 64);
  vf[0][0] = *(const bf16x8*)(vb + (size_t)0 * 16 * NN + 0);
  vf[0][1] = *(const bf16x8*)(vb + (size_t)1 * 16 * NN + 0);
  vf[0][2] = *(const bf16x8*)(vb + (size_t)0 * 16 * NN + 32);
  vf[0][3] = *(const bf16x8*)(vb + (size_t)1 * 16 * NN + 32);

  for (int it2 = 0; it2 < 32; ++it2) {
#pragma unroll
    for (int ph = 0; ph < 2; ++ph) {
      const int m0 = it2 * 128 + ph * 64;
      const int mn = (m0 + 64) & (NN - 1);  // next tile (wraps once, harmless)

      // ---- S^T slice: this wave's 32 m x 16 n ----
      f32x4 s0 = __builtin_amdgcn_mfma_f32_16x16x32_bf16(kf[ph][0], qf, fzero, 0, 0, 0);
      f32x4 s1 = __builtin_amdgcn_mfma_f32_16x16x32_bf16(kf[ph][1], qf, fzero, 0, 0, 0);

      // ---- prefetch next tile into the other set (full iter of slack) ----
      kf[ph ^ 1][0] = *(const bf16x8*)(kb + (size_t)(mn + wm * 16) * 64);
      kf[ph ^ 1][1] = *(const bf16x8*)(kb + (size_t)(mn + wm * 16 + 16) * 64);
      vf[ph ^ 1][0] = *(const bf16x8*)(vb + (size_t)0 * 16 * NN + mn);
      vf[ph ^ 1][1] = *(const bf16x8*)(vb + (size_t)1 * 16 * NN + mn);
      vf[ph ^ 1][2] = *(const bf16x8*)(vb + (size_t)0 * 16 * NN + mn + 32);
      vf[ph ^ 1][3] = *(const bf16x8*)(vb + (size_t)1 * 16 * NN + mn + 32);

      // ---- p = exp2(s); row-sum; pack 4 bf16 -> b64 writes ----
      char* pbase = (char*)Pb + ph * 8192 + prow * 128;
      {
        float p0 = __builtin_amdgcn_exp2f(s0[0]);
        float p1 = __builtin_amdgcn_exp2f(s0[1]);
        float p2 = __builtin_amdgcn_exp2f(s0[2]);
        float p3 = __builtin_amdgcn_exp2f(s0[3]);
        lsum += (p0 + p1) + (p2 + p3);
        uint2 pw;
        pw.x = __builtin_amdgcn_perm(__float_as_uint(p1) + 0x8000u,
                                     __float_as_uint(p0) + 0x8000u, 0x07060302u);
        pw.y = __builtin_amdgcn_perm(__float_as_uint(p3) + 0x8000u,
                                     __float_as_uint(p2) + 0x8000u, 0x07060302u);
        *(uint2*)(pbase + ((wm * 32 + g * 8) ^ wswz)) = pw;
      }
      {
        float p0 = __builtin_amdgcn_exp2f(s1[0]);
        float p1 = __builtin_amdgcn_exp2f(s1[1]);
        float p2 = __builtin_amdgcn_exp2f(s1[2]);
        float p3 = __builtin_amdgcn_exp2f(s1[3]);
        lsum += (p0 + p1) + (p2 + p3);
        uint2 pw;
        pw.x = __builtin_amdgcn_perm(__float_as_uint(p1) + 0x8000u,
                                     __float_as_uint(p0) + 0x8000u, 0x07060302u);
        pw.y = __builtin_amdgcn_perm(__float_as_uint(p3) + 0x8000u,
                                     __float_as_uint(p2) + 0x8000u, 0x07060302u);
        *(uint2*)(pbase + (((wm + 1) * 32 + g * 8) ^ wswz)) = pw;
      }

      // ---- barrier: drain DS only; global loads stay in flight ----
      __builtin_amdgcn_sched_barrier(0);
      asm volatile("s_waitcnt lgkmcnt(0)");
      __builtin_amdgcn_s_barrier();
      __builtin_amdgcn_sched_barrier(0);

      // ---- O^T += V * P  (own 32-channel slice x all 64 n) ----
      const char* prb = (const char*)Pb + ph * 8192;
#pragma unroll
      for (int nt = 0; nt < 4; ++nt) {
        const int row = nt * 16 + lr;
        const int rswz = (row & 7) << 4;
        bf16x8 a0 = *(const bf16x8*)(prb + row * 128 + ((g * 16) ^ rswz));
        bf16x8 a1 = *(const bf16x8*)(prb + row * 128 + ((64 + g * 16) ^ rswz));
#pragma unroll
        for (int ct = 0; ct < 2; ++ct) {
          oacc[nt][ct] = __builtin_amdgcn_mfma_f32_16x16x32_bf16(vf[ph][ct], a0, oacc[nt][ct], 0, 0, 0);
          oacc[nt][ct] = __builtin_amdgcn_mfma_f32_16x16x32_bf16(vf[ph][ct + 2], a1, oacc[nt][ct], 0, 0, 0);
        }
      }
    }
  }

  // ---- epilogue: combine row sums across wave pairs, normalize, write ----
  lsum += __shfl_xor(lsum, 16);
  lsum += __shfl_xor(lsum, 32);
  if (l < 16) lpart[w][lr] = lsum;
  __syncthreads();

  const size_t bbase = (size_t)b * CH * NN;
#pragma unroll
  for (int nt = 0; nt < 4; ++nt) {
    const float linv = 1.f / (lpart[nt][lr] + lpart[nt + 4][lr]);
    const int ncol = n0 + nt * 16 + lr;
#pragma unroll
    for (int ct = 0; ct < 2; ++ct) {
      const int cbase = w * 32 + ct * 16 + g * 4;
#pragma unroll
      for (int r = 0; r < 4; ++r) {
        const size_t off = bbase + (size_t)(cbase + r) * NN + ncol;
        out[off] = gamma0 * (oacc[nt][ct][r] * linv) + x[off];
      }
    }
  }
}

// ---------------------------------------------------------------------------
extern "C" void kernel_launch(void* const* d_in, const int* in_sizes, int n_in,
                              void* d_out, int out_size, void* d_ws, size_t ws_size,
                              hipStream_t stream) {
  const float* x     = (const float*)d_in[0];
  const float* Wq    = (const float*)d_in[1];
  const float* bq    = (const float*)d_in[2];
  const float* Wk    = (const float*)d_in[3];
  const float* bk    = (const float*)d_in[4];
  const float* Wv    = (const float*)d_in[5];
  const float* bv    = (const float*)d_in[6];
  const float* gamma = (const float*)d_in[7];
  float* out = (float*)d_out;

  char* ws = (char*)d_ws;
  u16*   xT  = (u16*)(ws);                 // [B,N,C] bf16   16,777,216 B
  u16*   qkb = (u16*)(ws + 16777216);      // [B,N,64] bf16   4,194,304 B
  u16*   vb  = (u16*)(ws + 20971520);      // [B,C,N] bf16   16,777,216 B
  u16*   Wqk = (u16*)(ws + 37748736);      // [64,256] bf16      32,768 B
  u16*   Wvb = (u16*)(ws + 37781504);      // [256,256] bf16    131,072 B
  float* bqk = (float*)(ws + 37912576);    // [64] f32              256 B

  prep_weights<<<256, 256, 0, stream>>>(Wq, bq, Wk, bk, Wv, Wqk, Wvb, bqk);
  transpose_x<<<dim3(64, 4, 8), 256, 0, stream>>>(x, xT);
  gemm_proj<<<dim3(64, 1, 8), 256, 0, stream>>>(
      xT, (long long)NN * CH, Wqk, 0,
      nullptr, bqk, 0, 1,
      qkb, (long long)NN * 64, 64);
  gemm_proj<<<dim3(4, 64, 8), 256, 0, stream>>>(
      Wvb, 0, xT, (long long)NN * CH,
      bv, nullptr, 1, 0,
      vb, (long long)CH * NN, NN);
  attn_fused<<<dim3(64, 8), 512, 0, stream>>>(qkb, vb, x, gamma, out);
}